// Round 1
// baseline (373.243 us; speedup 1.0000x reference)
//
#include <hip/hip_runtime.h>
#include <cstdint>
#include <cstddef>

typedef __attribute__((ext_vector_type(8))) short bf16x8;
typedef __attribute__((ext_vector_type(4))) float f32x4;
typedef unsigned short u16;
typedef unsigned int u32;

__device__ __forceinline__ u16 f2bf(float f) {
  u32 u = __float_as_uint(f);
  u32 r = (u + 0x7fffu + ((u >> 16) & 1u)) >> 16;
  return (u16)r;
}
__device__ __forceinline__ float bf2f(u16 h) {
  return __uint_as_float(((u32)h) << 16);
}
__device__ __forceinline__ float fsilu(float v) { return v / (1.f + __expf(-v)); }
__device__ __forceinline__ float fsigmoid(float v) { return 1.f / (1.f + __expf(-v)); }

__device__ __forceinline__ void glds16(const void* g, void* l) {
  __builtin_amdgcn_global_load_lds(
      (const __attribute__((address_space(1))) void*)g,
      (__attribute__((address_space(3))) void*)l, 16, 0, 0);
}

// ---------------- cast / transpose ----------------

__global__ __launch_bounds__(256) void cast_bf16_vec(const float* __restrict__ src,
                                                     u16* __restrict__ dst, int n4) {
  int i = blockIdx.x * 256 + threadIdx.x;
  if (i >= n4) return;
  const float4 v = ((const float4*)src)[i];
  ushort4 o;
  o.x = f2bf(v.x); o.y = f2bf(v.y); o.z = f2bf(v.z); o.w = f2bf(v.w);
  ((ushort4*)dst)[i] = o;
}

// src: R x C f32 row-major  ->  dst: C x R bf16 row-major
__global__ void transpose_cast(const float* __restrict__ src, u16* __restrict__ dst,
                               int R, int C) {
  __shared__ float tile[32][33];
  int bx = blockIdx.x * 32;  // col base
  int by = blockIdx.y * 32;  // row base
  int tx = threadIdx.x, ty = threadIdx.y;  // (32,8)
#pragma unroll
  for (int i = 0; i < 4; ++i)
    tile[ty + i * 8][tx] = src[(size_t)(by + ty + i * 8) * C + bx + tx];
  __syncthreads();
#pragma unroll
  for (int i = 0; i < 4; ++i)
    dst[(size_t)(bx + ty + i * 8) * R + by + tx] = f2bf(tile[tx][ty + i * 8]);
}

// ---------------- GEMM (A: MxK bf16 rm, Bt: NxK bf16 rm) ----------------
// EPI 0: silu -> bf16     EPI 1: +bias, col<1024 ? tanh : sigmoid -> bf16

template <int EPI>
__global__ __launch_bounds__(256, 2) void gemm_bt(const u16* __restrict__ A,
                                                  const u16* __restrict__ Bt,
                                                  u16* __restrict__ C,
                                                  const float* __restrict__ bias,
                                                  int M, int N, int K) {
  __shared__ u16 lA[128 * 32];
  __shared__ u16 lB[128 * 32];
  const int tid = threadIdx.x;
  const int lane = tid & 63;
  const int wid = tid >> 6;
  const int wr = wid >> 1, wc = wid & 1;
  const long bm = (long)blockIdx.y * 128;
  const long bn = (long)blockIdx.x * 128;

  f32x4 acc[4][4] = {};

  const int srow = tid >> 2;        // 0..63
  const int skoff = (tid & 3) * 8;  // k element offset
  const u16* gA = A + (bm + srow) * (long)K + skoff;
  const u16* gB = Bt + (bn + srow) * (long)K + skoff;
  u16* lA0 = &lA[srow * 32 + skoff];
  u16* lA1 = &lA[(64 + srow) * 32 + skoff];
  u16* lB0 = &lB[srow * 32 + skoff];
  u16* lB1 = &lB[(64 + srow) * 32 + skoff];

  const int fr = lane & 15;
  const int fk = (lane >> 4) * 8;
  const u16* pA = &lA[(wr * 64 + fr) * 32 + fk];
  const u16* pB = &lB[(wc * 64 + fr) * 32 + fk];

  for (int kk = 0; kk < K; kk += 32) {
    glds16(gA + kk, lA0);
    glds16(gA + 64 * (long)K + kk, lA1);
    glds16(gB + kk, lB0);
    glds16(gB + 64 * (long)K + kk, lB1);
    __syncthreads();
    bf16x8 af[4], bf[4];
#pragma unroll
    for (int m = 0; m < 4; ++m) af[m] = *(const bf16x8*)(pA + m * 16 * 32);
#pragma unroll
    for (int n = 0; n < 4; ++n) bf[n] = *(const bf16x8*)(pB + n * 16 * 32);
#pragma unroll
    for (int m = 0; m < 4; ++m)
#pragma unroll
      for (int n = 0; n < 4; ++n)
        acc[m][n] =
            __builtin_amdgcn_mfma_f32_16x16x32_bf16(af[m], bf[n], acc[m][n], 0, 0, 0);
    __syncthreads();
  }

  const int erow0 = (lane >> 4) * 4;
  const int ecol = lane & 15;
#pragma unroll
  for (int m = 0; m < 4; ++m) {
#pragma unroll
    for (int n = 0; n < 4; ++n) {
#pragma unroll
      for (int j = 0; j < 4; ++j) {
        long row = bm + wr * 64 + m * 16 + erow0 + j;
        long col = bn + wc * 64 + n * 16 + ecol;
        float v = acc[m][n][j];
        if (EPI == 0) {
          v = fsilu(v);
        } else {
          v += bias[col];
          v = (col < 1024) ? tanhf(v) : fsigmoid(v);
        }
        C[row * (long)N + col] = f2bf(v);
      }
    }
  }
}

// ---------------- gated scan (3-pass chunked) ----------------
// sa layout: (B*T) x 2048 bf16; [.,0:1024)=tanh(theta), [.,1024:2048)=sigmoid(alpha)
// channels: B*D = 4096; chunks: 64 of length 64 along T.

__global__ __launch_bounds__(256) void scan_stage1(const u16* __restrict__ sa,
                                                   float* __restrict__ cA,
                                                   float* __restrict__ cB) {
  const int tid = blockIdx.x * 256 + threadIdx.x;  // 0..262143
  const int d = tid & 1023;
  const int chunk = (tid >> 10) & 63;
  const int b = tid >> 16;
  const size_t base = ((size_t)(b * 4096 + chunk * 64)) * 2048 + d;
  float Ac = 1.f, Bc = 0.f;
#pragma unroll 4
  for (int t = 0; t < 64; ++t) {
    float s = bf2f(sa[base + (size_t)t * 2048]);
    float a = bf2f(sa[base + (size_t)t * 2048 + 1024]);
    Bc = a * Bc + (1.f - a) * s;
    Ac *= a;
  }
  cA[tid] = Ac;
  cB[tid] = Bc;
}

__global__ __launch_bounds__(256) void scan_stage2(const float* __restrict__ cA,
                                                   const float* __restrict__ cB,
                                                   float* __restrict__ hstart) {
  const int tid = blockIdx.x * 256 + threadIdx.x;  // 0..4095
  const int d = tid & 1023;
  const int b = tid >> 10;
  float h = 0.f;
  for (int c = 0; c < 64; ++c) {
    const size_t i = ((size_t)(b * 64 + c)) * 1024 + d;
    hstart[i] = h;
    h = cA[i] * h + cB[i];
  }
}

__global__ __launch_bounds__(256) void scan_stage3(const u16* __restrict__ sa,
                                                   const float* __restrict__ hstart,
                                                   float* __restrict__ sem) {
  const int tid = blockIdx.x * 256 + threadIdx.x;
  const int d = tid & 1023;
  const int chunk = (tid >> 10) & 63;
  const int b = tid >> 16;
  const size_t m0 = (size_t)(b * 4096 + chunk * 64);
  const size_t base = m0 * 2048 + d;
  float h = hstart[tid];
#pragma unroll 4
  for (int t = 0; t < 64; ++t) {
    float s = bf2f(sa[base + (size_t)t * 2048]);
    float a = bf2f(sa[base + (size_t)t * 2048 + 1024]);
    h = a * h + (1.f - a) * s;
    sem[(m0 + t) * 1024 + d] = h;
  }
}

// ---------------- conv + LN + L2 ----------------

__global__ __launch_bounds__(256) void finalize(const float* __restrict__ sem,
                                                const float* __restrict__ cw,
                                                const float* __restrict__ gamma,
                                                const float* __restrict__ beta,
                                                float* __restrict__ out) {
  const int r = blockIdx.x;   // 0..16383
  const int t = r & 4095;     // T = 4096
  const int tid = threadIdx.x;
  const int lane = tid & 63, wid = tid >> 6;
  const int d0 = tid * 4;
  const float4 zero = make_float4(0.f, 0.f, 0.f, 0.f);
  float4 s0 = ((const float4*)(sem + (size_t)r * 1024))[tid];
  float4 s1 = (t >= 1) ? ((const float4*)(sem + (size_t)(r - 1) * 1024))[tid] : zero;
  float4 s2 = (t >= 2) ? ((const float4*)(sem + (size_t)(r - 2) * 1024))[tid] : zero;
  float a0[4] = {s0.x, s0.y, s0.z, s0.w};
  float a1[4] = {s1.x, s1.y, s1.z, s1.w};
  float a2[4] = {s2.x, s2.y, s2.z, s2.w};
  float y[4];
  float vs = 0.f, vq = 0.f;
#pragma unroll
  for (int j = 0; j < 4; ++j) {
    int d = d0 + j;
    float cb = cw[d * 3] * a2[j] + cw[d * 3 + 1] * a1[j] + cw[d * 3 + 2] * a0[j];
    cb = fsilu(cb);
    y[j] = a0[j] + 0.1f * cb;
    vs += y[j];
    vq += y[j] * y[j];
  }
  __shared__ float rb[2][4];
#pragma unroll
  for (int o = 32; o > 0; o >>= 1) {
    vs += __shfl_down(vs, o);
    vq += __shfl_down(vq, o);
  }
  if (lane == 0) { rb[0][wid] = vs; rb[1][wid] = vq; }
  __syncthreads();
  float tsum = rb[0][0] + rb[0][1] + rb[0][2] + rb[0][3];
  float tss = rb[1][0] + rb[1][1] + rb[1][2] + rb[1][3];
  float mu = tsum * (1.f / 1024.f);
  float var = tss * (1.f / 1024.f) - mu * mu;
  float rstd = rsqrtf(var + 1e-5f);
  float yn[4];
  float q = 0.f;
#pragma unroll
  for (int j = 0; j < 4; ++j) {
    int d = d0 + j;
    yn[j] = (y[j] - mu) * rstd * gamma[d] + beta[d];
    q += yn[j] * yn[j];
  }
#pragma unroll
  for (int o = 32; o > 0; o >>= 1) q += __shfl_down(q, o);
  __syncthreads();
  if (lane == 0) rb[0][wid] = q;
  __syncthreads();
  float nrm = sqrtf(rb[0][0] + rb[0][1] + rb[0][2] + rb[0][3]);
  float scale = 1.f / fmaxf(nrm, 1e-12f);
  float4 o4 = make_float4(yn[0] * scale, yn[1] * scale, yn[2] * scale, yn[3] * scale);
  ((float4*)(out + (size_t)r * 1024))[tid] = o4;
}

// ---------------- launch ----------------

extern "C" void kernel_launch(void* const* d_in, const int* in_sizes, int n_in,
                              void* d_out, int out_size, void* d_ws, size_t ws_size,
                              hipStream_t stream) {
  const float* x = (const float*)d_in[0];
  const float* W1 = (const float*)d_in[1];
  const float* W2 = (const float*)d_in[2];
  const float* b2 = (const float*)d_in[3];
  const float* cw = (const float*)d_in[4];
  const float* gamma = (const float*)d_in[5];
  const float* beta = (const float*)d_in[6];
  float* out = (float*)d_out;
  char* ws = (char*)d_ws;

  // workspace layout (bytes):
  // [0,32M)    xb  (bf16 x)           -- dead after gemm1; reused by cA/cB/hstart
  // [32M,36M)  w1t (bf16 W1^T)
  // [36M,44M)  w2t (bf16 W2^T)
  // [44M,108M) h1  (bf16, 16384x2048) -- dead after gemm2; reused as sem (f32 16384x1024)
  // [108M,172M) sa (bf16, 16384x2048) tanh(theta) | sigmoid(alpha)
  u16* xb = (u16*)(ws);
  u16* w1t = (u16*)(ws + 33554432);
  u16* w2t = (u16*)(ws + 37748736);
  u16* h1 = (u16*)(ws + 46137344);
  float* sem = (float*)(ws + 46137344);
  u16* sa = (u16*)(ws + 113246208);
  float* cA = (float*)(ws);
  float* cB = (float*)(ws + 1048576);
  float* hstart = (float*)(ws + 2097152);

  cast_bf16_vec<<<16384, 256, 0, stream>>>(x, xb, 4194304);
  transpose_cast<<<dim3(64, 32), dim3(32, 8), 0, stream>>>(W1, w1t, 1024, 2048);
  transpose_cast<<<dim3(64, 64), dim3(32, 8), 0, stream>>>(W2, w2t, 2048, 2048);
  gemm_bt<0><<<dim3(16, 128), 256, 0, stream>>>(xb, w1t, h1, nullptr, 16384, 2048, 1024);
  gemm_bt<1><<<dim3(16, 128), 256, 0, stream>>>(h1, w2t, sa, b2, 16384, 2048, 2048);
  scan_stage1<<<1024, 256, 0, stream>>>(sa, cA, cB);
  scan_stage2<<<16, 256, 0, stream>>>(cA, cB, hstart);
  scan_stage3<<<1024, 256, 0, stream>>>(sa, hstart, sem);
  finalize<<<16384, 256, 0, stream>>>(sem, cw, gamma, beta, out);
}